// Round 11
// baseline (103.091 us; speedup 1.0000x reference)
//
#include <hip/hip_runtime.h>
#include <float.h>

// Chamfer L2, B=4, N=M=8192 fp32 -> scalar.
// bf16 MFMA path (v_mfma_f32_32x32x16_bf16), distance fully K-packed (K=16):
//   A[k] = [qh(3), ql(3), qh(3), ql(3), 1, 1, qnh, qnl]
//   B[k] = [ph(3), ph(3), pl(3), pl(3), wh, wl, 1, 1]
//   acc = q.p - 0.5|p|^2 - 0.5|q|^2 = -0.5 d ; min d = -2 max acc.
// R10 fixed bank conflicts ([half][point] LDS) but spilled registers:
// launch_bounds(256,4) = 128-reg cap vs ~150 needed (WRITE_SIZE 14.3MB of
// scratch evictions vs 2MB actual output). R11: QA=2 (~100 regs),
// launch_bounds(256,2), and 2-tile unroll with v_max3 epilogue
// (runmax = max3(runmax, acc_t0, acc_t1) -> 0.5 VALU op per pair).
// C layout (HW-verified): col=lane&31, row=(reg&3)+8*(reg>>2)+4*(lane>>5).

typedef short sh8    __attribute__((ext_vector_type(8)));
typedef float f32x16 __attribute__((ext_vector_type(16)));

#define BLK   256
#define BATCH 4
#define NPTS  8192
#define PCH   8                      // point chunks
#define PCHUNK (NPTS / PCH)          // 1024 points staged (32 KB LDS)
#define QA    2                      // A fragments per wave
#define QPW   (QA * 32)              // 64 queries per wave
#define QPB   (4 * QPW)              // 256 queries per block
#define QTILES (NPTS / QPB)          // 32
#define GRID  (2 * BATCH * QTILES * PCH)  // 2048
#define TOTQ  (2 * BATCH * NPTS)          // 65536
#define WS_NEED ((size_t)PCH * TOTQ * sizeof(float))  // 2 MB
#define ONEBF 0x3F80

__device__ __forceinline__ short f2bf(float f) {
    unsigned u = __float_as_uint(f);
    unsigned r = (u + 0x7FFFu + ((u >> 16) & 1u)) >> 16;
    return (short)r;
}
__device__ __forceinline__ float bf2f(short h) {
    return __uint_as_float(((unsigned)(unsigned short)h) << 16);
}

__global__ void zero_out_kernel(float* out) { out[0] = 0.f; }

__global__ __launch_bounds__(BLK, 2) void cd_mfma_kernel(
    const float* __restrict__ p1, const float* __restrict__ p2,
    float* __restrict__ part)
{
    __shared__ uint4 ptsB[2 * PCHUNK];   // [half][point], 32 KB

    int bid    = blockIdx.x;
    int pchunk = bid & (PCH - 1);
    int qt     = (bid >> 3) & (QTILES - 1);
    int batch  = (bid >> 8) & (BATCH - 1);
    int dir    = bid >> 10;

    const float* qbase = (dir == 0 ? p1 : p2) + (size_t)batch * NPTS * 3;
    const float* dbase = (dir == 0 ? p2 : p1) + (size_t)batch * NPTS * 3;

    int tid  = threadIdx.x;
    int wave = tid >> 6;
    int lane = tid & 63;
    int col  = lane & 31;
    int half = lane >> 5;

    // ---- stage 1024 points, 1 point/thread x 4 iters (stores stride 16B) ----
    #pragma unroll
    for (int it = 0; it < PCHUNK / BLK; ++it) {
        int p = tid + it * BLK;
        const float* s = dbase + (size_t)(pchunk * PCHUNK + p) * 3;
        float x = s[0], y = s[1], z = s[2];
        short hx = f2bf(x), hy = f2bf(y), hz = f2bf(z);
        short lx = f2bf(x - bf2f(hx));
        short ly = f2bf(y - bf2f(hy));
        short lz = f2bf(z - bf2f(hz));
        float w = -0.5f * (x * x + y * y + z * z);
        short wh = f2bf(w);
        short wl = f2bf(w - bf2f(wh));
        unsigned uhx = (unsigned short)hx, uhy = (unsigned short)hy, uhz = (unsigned short)hz;
        unsigned ulx = (unsigned short)lx, uly = (unsigned short)ly, ulz = (unsigned short)lz;
        // half0 shorts: [phx phy phz phx phy phz plx ply]
        ptsB[p] = make_uint4(uhx | (uhy << 16), uhz | (uhx << 16),
                             uhy | (uhz << 16), ulx | (uly << 16));
        // half1 shorts: [plz plx ply plz wh wl 1 1]
        ptsB[PCHUNK + p] = make_uint4(
            ulz | (ulx << 16), uly | (ulz << 16),
            (unsigned)(unsigned short)wh | ((unsigned)(unsigned short)wl << 16),
            ((unsigned)ONEBF) | (((unsigned)ONEBF) << 16));
    }

    // ---- A fragments: QA query groups of 32 per wave ----
    sh8 afrag[QA];
    #pragma unroll
    for (int qa = 0; qa < QA; ++qa) {
        int q = qt * QPB + wave * QPW + qa * 32 + col;
        const float* s = qbase + (size_t)q * 3;
        float x = s[0], y = s[1], z = s[2];
        short hx = f2bf(x), hy = f2bf(y), hz = f2bf(z);
        short lx = f2bf(x - bf2f(hx));
        short ly = f2bf(y - bf2f(hy));
        short lz = f2bf(z - bf2f(hz));
        float w = -0.5f * (x * x + y * y + z * z);
        short nh = f2bf(w);
        short nl = f2bf(w - bf2f(nh));
        // half0: [qhx qhy qhz qlx qly qlz qhx qhy]
        // half1: [qhz qlx qly qlz  1   1  qnh qnl]
        afrag[qa][0] = half ? hz : hx;
        afrag[qa][1] = half ? lx : hy;
        afrag[qa][2] = half ? ly : hz;
        afrag[qa][3] = half ? lz : lx;
        afrag[qa][4] = half ? (short)ONEBF : ly;
        afrag[qa][5] = half ? (short)ONEBF : lz;
        afrag[qa][6] = half ? nh : hx;
        afrag[qa][7] = half ? nl : hy;
    }
    __syncthreads();

    f32x16 zc;
    f32x16 runmax[QA];
    #pragma unroll
    for (int i = 0; i < 16; ++i) zc[i] = 0.f;
    #pragma unroll
    for (int qa = 0; qa < QA; ++qa)
        #pragma unroll
        for (int i = 0; i < 16; ++i) runmax[qa][i] = -FLT_MAX;

    const uint4* bbase = ptsB + half * PCHUNK + col;

    // ---- 32 tiles of 32 points, 2 tiles/iter; v_max3 epilogue ----
    #pragma unroll 2
    for (int t = 0; t < PCHUNK / 32; t += 2) {
        sh8 b0 = *(const sh8*)(bbase + t * 32);
        sh8 b1 = *(const sh8*)(bbase + (t + 1) * 32);
        #pragma unroll
        for (int qa = 0; qa < QA; ++qa) {
            f32x16 a0 = __builtin_amdgcn_mfma_f32_32x32x16_bf16(
                afrag[qa], b0, zc, 0, 0, 0);
            f32x16 a1 = __builtin_amdgcn_mfma_f32_32x32x16_bf16(
                afrag[qa], b1, zc, 0, 0, 0);
            runmax[qa] = __builtin_elementwise_max(
                runmax[qa], __builtin_elementwise_max(a0, a1));  // v_max3
        }
    }

    // ---- row-reduce over 32 col-lanes, then store 32 rows per qa ----
    int qglob0 = dir * (BATCH * NPTS) + batch * NPTS + qt * QPB + wave * QPW;
    float* prow = part + (size_t)pchunk * TOTQ + qglob0;
    #pragma unroll
    for (int qa = 0; qa < QA; ++qa) {
        f32x16 rm = runmax[qa];
        #pragma unroll
        for (int step = 1; step <= 16; step <<= 1) {
            f32x16 o;
            #pragma unroll
            for (int i = 0; i < 16; ++i) o[i] = __shfl_xor(rm[i], step, 64);
            rm = __builtin_elementwise_max(rm, o);
        }
        if (col == 0) {
            #pragma unroll
            for (int reg = 0; reg < 16; ++reg) {
                int r = (reg & 3) + 8 * (reg >> 2) + 4 * half;
                prow[qa * 32 + r] = fmaxf(-2.f * rm[reg], 0.f);
            }
        }
    }
}

// Stage 2: per query min over PCH chunks, then block-sum -> atomicAdd out.
__global__ __launch_bounds__(BLK) void min_sum_kernel(
    const float* __restrict__ part, float* __restrict__ out, float scale)
{
    int qid = blockIdx.x * BLK + threadIdx.x;
    float v = FLT_MAX;
    #pragma unroll
    for (int m = 0; m < PCH; ++m)
        v = fminf(v, part[(size_t)m * TOTQ + qid]);
    for (int off = 32; off > 0; off >>= 1) v += __shfl_down(v, off, 64);
    __shared__ float wsum[BLK / 64];
    int lane = threadIdx.x & 63, wid = threadIdx.x >> 6;
    if (lane == 0) wsum[wid] = v;
    __syncthreads();
    if (threadIdx.x == 0) {
        float t = 0.f;
        for (int w = 0; w < BLK / 64; ++w) t += wsum[w];
        atomicAdd(out, t * scale);
    }
}

// ---- fallback path (ws too small): fp32 VALU + atomicMin ----
typedef float v2f __attribute__((ext_vector_type(2)));
typedef float v4f __attribute__((ext_vector_type(4)));
#define FQPT   8
#define FNCH   32
#define FCHUNK (NPTS / FNCH)

__global__ __launch_bounds__(BLK) void init_kernel(unsigned* mins, float* out, int n) {
    int i = blockIdx.x * BLK + threadIdx.x;
    if (i < n) mins[i] = 0x7F7FFFFFu;
    if (i == 0) out[0] = 0.f;
}

__global__ __launch_bounds__(BLK) void cd_chunk_atomic_kernel(
    const float* __restrict__ p1, const float* __restrict__ p2,
    unsigned* __restrict__ mins)
{
    __shared__ v4f pts[FCHUNK];
    int bid    = blockIdx.x;
    int mchunk = bid & (FNCH - 1);
    int qt     = (bid >> 5) & 3;
    int batch  = (bid >> 7) & (BATCH - 1);
    int dir    = bid >> 9;
    const float* qbase = (dir == 0 ? p1 : p2) + (size_t)batch * NPTS * 3;
    const float* dbase = (dir == 0 ? p2 : p1) + (size_t)batch * NPTS * 3;
    int tid = threadIdx.x;
    if (tid < FCHUNK / 4) {
        int t4 = tid * 4;
        const float* s = dbase + (size_t)(mchunk * FCHUNK + t4) * 3;
        float4 f0 = *(const float4*)(s);
        float4 f1 = *(const float4*)(s + 4);
        float4 f2 = *(const float4*)(s + 8);
        float x0 = f0.x, y0 = f0.y, z0 = f0.z;
        float x1 = f0.w, y1 = f1.x, z1 = f1.y;
        float x2 = f1.z, y2 = f1.w, z2 = f2.x;
        float x3 = f2.y, y3 = f2.z, z3 = f2.w;
        float w0 = -0.5f * (x0*x0 + y0*y0 + z0*z0);
        float w1 = -0.5f * (x1*x1 + y1*y1 + z1*z1);
        float w2 = -0.5f * (x2*x2 + y2*y2 + z2*z2);
        float w3 = -0.5f * (x3*x3 + y3*y3 + z3*z3);
        pts[4*tid + 0] = (v4f){x0, x1, y0, y1};
        pts[4*tid + 1] = (v4f){z0, z1, w0, w1};
        pts[4*tid + 2] = (v4f){x2, x3, y2, y3};
        pts[4*tid + 3] = (v4f){z2, z3, w2, w3};
    }
    v2f qx2[FQPT], qy2[FQPT], qz2[FQPT];
    float qn[FQPT];
    #pragma unroll
    for (int k = 0; k < FQPT; ++k) {
        int q = qt * (BLK * FQPT) + k * BLK + tid;
        const float* s = qbase + (size_t)q * 3;
        float qx = s[0], qy = s[1], qz = s[2];
        qx2[k] = (v2f){qx, qx}; qy2[k] = (v2f){qy, qy}; qz2[k] = (v2f){qz, qz};
        qn[k] = qx * qx + qy * qy + qz * qz;
    }
    __syncthreads();
    v2f acc0[FQPT], acc1[FQPT];
    #pragma unroll
    for (int k = 0; k < FQPT; ++k) {
        acc0[k] = (v2f){-FLT_MAX, -FLT_MAX};
        acc1[k] = (v2f){-FLT_MAX, -FLT_MAX};
    }
    #pragma unroll 2
    for (int m = 0; m < FCHUNK / 2; m += 2) {
        v4f u0 = pts[2*m + 0], v0 = pts[2*m + 1];
        v4f u1 = pts[2*m + 2], v1 = pts[2*m + 3];
        v2f X0 = __builtin_shufflevector(u0, u0, 0, 1);
        v2f Y0 = __builtin_shufflevector(u0, u0, 2, 3);
        v2f Z0 = __builtin_shufflevector(v0, v0, 0, 1);
        v2f W0 = __builtin_shufflevector(v0, v0, 2, 3);
        v2f X1 = __builtin_shufflevector(u1, u1, 0, 1);
        v2f Y1 = __builtin_shufflevector(u1, u1, 2, 3);
        v2f Z1 = __builtin_shufflevector(v1, v1, 0, 1);
        v2f W1 = __builtin_shufflevector(v1, v1, 2, 3);
        #pragma unroll
        for (int k = 0; k < FQPT; ++k) {
            v2f s0 = __builtin_elementwise_fma(qz2[k], Z0,
                      __builtin_elementwise_fma(qy2[k], Y0,
                       __builtin_elementwise_fma(qx2[k], X0, W0)));
            acc0[k] = __builtin_elementwise_max(acc0[k], s0);
            v2f s1 = __builtin_elementwise_fma(qz2[k], Z1,
                      __builtin_elementwise_fma(qy2[k], Y1,
                       __builtin_elementwise_fma(qx2[k], X1, W1)));
            acc1[k] = __builtin_elementwise_max(acc1[k], s1);
        }
    }
    unsigned qid = (unsigned)(dir * (BATCH * NPTS) + batch * NPTS + qt * (BLK * FQPT) + tid);
    #pragma unroll
    for (int k = 0; k < FQPT; ++k) {
        float mx = fmaxf(fmaxf(acc0[k].x, acc0[k].y), fmaxf(acc1[k].x, acc1[k].y));
        float d = fmaxf(qn[k] - 2.f * mx, 0.f);
        atomicMin(&mins[qid + k * BLK], __float_as_uint(d));
    }
}

__global__ __launch_bounds__(BLK) void sum_kernel(
    const unsigned* __restrict__ mins, float* __restrict__ out, int n, float scale)
{
    int i = blockIdx.x * BLK + threadIdx.x;
    int stride = gridDim.x * BLK;
    float v = 0.f;
    for (int idx = i; idx < n; idx += stride) v += __uint_as_float(mins[idx]);
    for (int off = 32; off > 0; off >>= 1) v += __shfl_down(v, off, 64);
    __shared__ float wsum[BLK / 64];
    int lane = threadIdx.x & 63, wid = threadIdx.x >> 6;
    if (lane == 0) wsum[wid] = v;
    __syncthreads();
    if (threadIdx.x == 0) {
        float t = 0.f;
        for (int w = 0; w < BLK / 64; ++w) t += wsum[w];
        atomicAdd(out, t * scale);
    }
}

extern "C" void kernel_launch(void* const* d_in, const int* in_sizes, int n_in,
                              void* d_out, int out_size, void* d_ws, size_t ws_size,
                              hipStream_t stream) {
    const float* p1 = (const float*)d_in[0];
    const float* p2 = (const float*)d_in[1];
    float* out = (float*)d_out;

    if (ws_size >= WS_NEED) {
        float* part = (float*)d_ws;
        zero_out_kernel<<<1, 1, 0, stream>>>(out);
        cd_mfma_kernel<<<GRID, BLK, 0, stream>>>(p1, p2, part);
        min_sum_kernel<<<TOTQ / BLK, BLK, 0, stream>>>(part, out,
                                                       1.f / (float)(BATCH * NPTS));
    } else {
        unsigned* mins = (unsigned*)d_ws;
        init_kernel<<<TOTQ / BLK, BLK, 0, stream>>>(mins, out, TOTQ);
        cd_chunk_atomic_kernel<<<1024, BLK, 0, stream>>>(p1, p2, mins);
        sum_kernel<<<64, BLK, 0, stream>>>(mins, out, TOTQ, 1.f / (float)(BATCH * NPTS));
    }
}

// Round 12
// 99.422 us; speedup vs baseline: 1.0369x; 1.0369x over previous
//
#include <hip/hip_runtime.h>
#include <float.h>

// Chamfer L2, B=4, N=M=8192 fp32 -> scalar.
// bf16 MFMA, distance K-packed (K=16), SYMMETRIC-SCORE version:
//   s_ij = p1_i . p2_j - 0.5|p2_j|^2 - 0.5|p1_i|^2 = -0.5 d_ij
// One tile serves BOTH chamfer directions: row-max -> d1, col-max -> d2.
// R12: drop the dir dimension (R9-R11 computed every dot twice): MFMA count,
// staging, FETCH all halve. Col-max per tile: qa-combine + max3 reg-tree +
// cross-half shfl + LDS atomicMin on uint bits (float-max == uint-min for
// s <= 0). Row path unchanged (shfl tree over 32 col-lanes).
// C layout (HW-verified): col=lane&31, row=(reg&3)+8*(reg>>2)+4*(lane>>5).

typedef short sh8    __attribute__((ext_vector_type(8)));
typedef float f32x16 __attribute__((ext_vector_type(16)));

#define BLK   256
#define BATCH 4
#define NPTS  8192
#define PCH   8                      // point (col) chunks
#define PCHUNK (NPTS / PCH)          // 1024 points staged (32 KB LDS)
#define QA    2                      // A fragments per wave
#define QPW   (QA * 32)              // 64 rows per wave
#define QPB   (4 * QPW)              // 256 rows per block
#define QTILES (NPTS / QPB)          // 32
#define GRID  (BATCH * QTILES * PCH)      // 1024
#define NROW  (BATCH * NPTS)              // 32768 (rows; same count of cols)
#define WS_NEED ((size_t)(PCH + QTILES) * NROW * sizeof(float))  // 5.25 MB
#define ONEBF 0x3F80
#define NEGMAXU 0xFF7FFFFFu          // bits of -FLT_MAX

__device__ __forceinline__ short f2bf(float f) {
    unsigned u = __float_as_uint(f);
    unsigned r = (u + 0x7FFFu + ((u >> 16) & 1u)) >> 16;
    return (short)r;
}
__device__ __forceinline__ float bf2f(short h) {
    return __uint_as_float(((unsigned)(unsigned short)h) << 16);
}
__device__ __forceinline__ float tree_max16(f32x16 v) {
    // max3-friendly grouping: 8 instrs
    float a = fmaxf(fmaxf(v[0], v[1]), v[2]);
    float b = fmaxf(fmaxf(v[3], v[4]), v[5]);
    float c = fmaxf(fmaxf(v[6], v[7]), v[8]);
    float d = fmaxf(fmaxf(v[9], v[10]), v[11]);
    float e = fmaxf(fmaxf(v[12], v[13]), v[14]);
    float f = fmaxf(fmaxf(a, b), c);
    float g = fmaxf(fmaxf(d, e), v[15]);
    return fmaxf(f, g);
}

__global__ void zero_out_kernel(float* out) { out[0] = 0.f; }

__global__ __launch_bounds__(BLK, 2) void cd_mfma_kernel(
    const float* __restrict__ p1, const float* __restrict__ p2,
    float* __restrict__ part1, float* __restrict__ part2)
{
    __shared__ uint4 ptsB[2 * PCHUNK];     // [half][point], 32 KB
    __shared__ unsigned colbuf[PCHUNK];    // col-max bits, 4 KB

    int bid    = blockIdx.x;
    int pchunk = bid & (PCH - 1);
    int qt     = (bid >> 3) & (QTILES - 1);
    int batch  = bid >> 8;

    const float* qbase = p1 + (size_t)batch * NPTS * 3;   // rows
    const float* dbase = p2 + (size_t)batch * NPTS * 3;   // cols

    int tid  = threadIdx.x;
    int wave = tid >> 6;
    int lane = tid & 63;
    int col  = lane & 31;
    int half = lane >> 5;

    // ---- stage 1024 p2 points + init colbuf ----
    #pragma unroll
    for (int it = 0; it < PCHUNK / BLK; ++it) {
        int p = tid + it * BLK;
        colbuf[p] = NEGMAXU;
        const float* s = dbase + (size_t)(pchunk * PCHUNK + p) * 3;
        float x = s[0], y = s[1], z = s[2];
        short hx = f2bf(x), hy = f2bf(y), hz = f2bf(z);
        short lx = f2bf(x - bf2f(hx));
        short ly = f2bf(y - bf2f(hy));
        short lz = f2bf(z - bf2f(hz));
        float w = -0.5f * (x * x + y * y + z * z);
        short wh = f2bf(w);
        short wl = f2bf(w - bf2f(wh));
        unsigned uhx = (unsigned short)hx, uhy = (unsigned short)hy, uhz = (unsigned short)hz;
        unsigned ulx = (unsigned short)lx, uly = (unsigned short)ly, ulz = (unsigned short)lz;
        // half0 k0-7: [phx phy phz phx phy phz plx ply]
        ptsB[p] = make_uint4(uhx | (uhy << 16), uhz | (uhx << 16),
                             uhy | (uhz << 16), ulx | (uly << 16));
        // half1 k8-15: [plz plx ply plz wh wl 1 1]
        ptsB[PCHUNK + p] = make_uint4(
            ulz | (ulx << 16), uly | (ulz << 16),
            (unsigned)(unsigned short)wh | ((unsigned)(unsigned short)wl << 16),
            ((unsigned)ONEBF) | (((unsigned)ONEBF) << 16));
    }

    // ---- A fragments: QA row groups of 32 per wave (p1 queries) ----
    sh8 afrag[QA];
    #pragma unroll
    for (int qa = 0; qa < QA; ++qa) {
        int q = qt * QPB + wave * QPW + qa * 32 + col;
        const float* s = qbase + (size_t)q * 3;
        float x = s[0], y = s[1], z = s[2];
        short hx = f2bf(x), hy = f2bf(y), hz = f2bf(z);
        short lx = f2bf(x - bf2f(hx));
        short ly = f2bf(y - bf2f(hy));
        short lz = f2bf(z - bf2f(hz));
        float w = -0.5f * (x * x + y * y + z * z);
        short nh = f2bf(w);
        short nl = f2bf(w - bf2f(nh));
        // half0 k0-7: [qhx qhy qhz qlx qly qlz qhx qhy]
        // half1 k8-15:[qhz qlx qly qlz  1   1  qnh qnl]
        afrag[qa][0] = half ? hz : hx;
        afrag[qa][1] = half ? lx : hy;
        afrag[qa][2] = half ? ly : hz;
        afrag[qa][3] = half ? lz : lx;
        afrag[qa][4] = half ? (short)ONEBF : ly;
        afrag[qa][5] = half ? (short)ONEBF : lz;
        afrag[qa][6] = half ? nh : hx;
        afrag[qa][7] = half ? nl : hy;
    }
    __syncthreads();

    f32x16 zc;
    f32x16 runmax[QA];
    #pragma unroll
    for (int i = 0; i < 16; ++i) zc[i] = 0.f;
    #pragma unroll
    for (int qa = 0; qa < QA; ++qa)
        #pragma unroll
        for (int i = 0; i < 16; ++i) runmax[qa][i] = -FLT_MAX;

    const uint4* bbase = ptsB + half * PCHUNK + col;

    // ---- 32 tiles of 32 cols, 2 tiles/iter ----
    #pragma unroll 2
    for (int t = 0; t < PCHUNK / 32; t += 2) {
        sh8 b0 = *(const sh8*)(bbase + t * 32);
        sh8 b1 = *(const sh8*)(bbase + (t + 1) * 32);
        f32x16 a00 = __builtin_amdgcn_mfma_f32_32x32x16_bf16(afrag[0], b0, zc, 0, 0, 0);
        f32x16 a10 = __builtin_amdgcn_mfma_f32_32x32x16_bf16(afrag[1], b0, zc, 0, 0, 0);
        f32x16 a01 = __builtin_amdgcn_mfma_f32_32x32x16_bf16(afrag[0], b1, zc, 0, 0, 0);
        f32x16 a11 = __builtin_amdgcn_mfma_f32_32x32x16_bf16(afrag[1], b1, zc, 0, 0, 0);
        // row path: running max per row group (v_max3)
        runmax[0] = __builtin_elementwise_max(runmax[0],
                     __builtin_elementwise_max(a00, a01));
        runmax[1] = __builtin_elementwise_max(runmax[1],
                     __builtin_elementwise_max(a10, a11));
        // col path: per tile, combine row groups then reduce rows
        f32x16 c0 = __builtin_elementwise_max(a00, a10);
        f32x16 c1 = __builtin_elementwise_max(a01, a11);
        float m0 = tree_max16(c0);
        float m1 = tree_max16(c1);
        m0 = fmaxf(m0, __shfl_xor(m0, 32, 64));   // other half's rows
        m1 = fmaxf(m1, __shfl_xor(m1, 32, 64));
        atomicMin(&colbuf[t * 32 + col], __float_as_uint(m0));
        atomicMin(&colbuf[(t + 1) * 32 + col], __float_as_uint(m1));
    }

    // ---- row epilogue: shfl-reduce over 32 col-lanes -> part1 ----
    int row0 = batch * NPTS + qt * QPB + wave * QPW;
    float* prow = part1 + (size_t)pchunk * NROW + row0;
    #pragma unroll
    for (int qa = 0; qa < QA; ++qa) {
        f32x16 rm = runmax[qa];
        #pragma unroll
        for (int step = 1; step <= 16; step <<= 1) {
            f32x16 o;
            #pragma unroll
            for (int i = 0; i < 16; ++i) o[i] = __shfl_xor(rm[i], step, 64);
            rm = __builtin_elementwise_max(rm, o);
        }
        if (col == 0) {
            #pragma unroll
            for (int reg = 0; reg < 16; ++reg) {
                int r = (reg & 3) + 8 * (reg >> 2) + 4 * half;
                prow[qa * 32 + r] = fmaxf(-2.f * rm[reg], 0.f);
            }
        }
    }

    // ---- col epilogue: colbuf -> part2 ----
    __syncthreads();
    float* pcol = part2 + (size_t)qt * NROW + batch * NPTS + pchunk * PCHUNK;
    #pragma unroll
    for (int it = 0; it < PCHUNK / BLK; ++it) {
        int c = tid + it * BLK;
        float s = __uint_as_float(colbuf[c]);
        pcol[c] = fmaxf(-2.f * s, 0.f);
    }
}

// Stage 2: per row/col min over partials, block-sum -> atomicAdd out.
__global__ __launch_bounds__(BLK) void min_sum_kernel(
    const float* __restrict__ part, float* __restrict__ out,
    int nparts, float scale)
{
    int qid = blockIdx.x * BLK + threadIdx.x;
    float v = FLT_MAX;
    for (int m = 0; m < nparts; ++m)
        v = fminf(v, part[(size_t)m * NROW + qid]);
    for (int off = 32; off > 0; off >>= 1) v += __shfl_down(v, off, 64);
    __shared__ float wsum[BLK / 64];
    int lane = threadIdx.x & 63, wid = threadIdx.x >> 6;
    if (lane == 0) wsum[wid] = v;
    __syncthreads();
    if (threadIdx.x == 0) {
        float t = 0.f;
        for (int w = 0; w < BLK / 64; ++w) t += wsum[w];
        atomicAdd(out, t * scale);
    }
}

// ---- fallback path (ws too small): fp32 VALU + atomicMin ----
typedef float v2f __attribute__((ext_vector_type(2)));
typedef float v4f __attribute__((ext_vector_type(4)));
#define FQPT   8
#define FNCH   32
#define FCHUNK (NPTS / FNCH)
#define TOTQ  (2 * BATCH * NPTS)

__global__ __launch_bounds__(BLK) void init_kernel(unsigned* mins, float* out, int n) {
    int i = blockIdx.x * BLK + threadIdx.x;
    if (i < n) mins[i] = 0x7F7FFFFFu;
    if (i == 0) out[0] = 0.f;
}

__global__ __launch_bounds__(BLK) void cd_chunk_atomic_kernel(
    const float* __restrict__ p1, const float* __restrict__ p2,
    unsigned* __restrict__ mins)
{
    __shared__ v4f pts[FCHUNK];
    int bid    = blockIdx.x;
    int mchunk = bid & (FNCH - 1);
    int qt     = (bid >> 5) & 3;
    int batch  = (bid >> 7) & (BATCH - 1);
    int dir    = bid >> 9;
    const float* qbase = (dir == 0 ? p1 : p2) + (size_t)batch * NPTS * 3;
    const float* dbase = (dir == 0 ? p2 : p1) + (size_t)batch * NPTS * 3;
    int tid = threadIdx.x;
    if (tid < FCHUNK / 4) {
        int t4 = tid * 4;
        const float* s = dbase + (size_t)(mchunk * FCHUNK + t4) * 3;
        float4 f0 = *(const float4*)(s);
        float4 f1 = *(const float4*)(s + 4);
        float4 f2 = *(const float4*)(s + 8);
        float x0 = f0.x, y0 = f0.y, z0 = f0.z;
        float x1 = f0.w, y1 = f1.x, z1 = f1.y;
        float x2 = f1.z, y2 = f1.w, z2 = f2.x;
        float x3 = f2.y, y3 = f2.z, z3 = f2.w;
        float w0 = -0.5f * (x0*x0 + y0*y0 + z0*z0);
        float w1 = -0.5f * (x1*x1 + y1*y1 + z1*z1);
        float w2 = -0.5f * (x2*x2 + y2*y2 + z2*z2);
        float w3 = -0.5f * (x3*x3 + y3*y3 + z3*z3);
        pts[4*tid + 0] = (v4f){x0, x1, y0, y1};
        pts[4*tid + 1] = (v4f){z0, z1, w0, w1};
        pts[4*tid + 2] = (v4f){x2, x3, y2, y3};
        pts[4*tid + 3] = (v4f){z2, z3, w2, w3};
    }
    v2f qx2[FQPT], qy2[FQPT], qz2[FQPT];
    float qn[FQPT];
    #pragma unroll
    for (int k = 0; k < FQPT; ++k) {
        int q = qt * (BLK * FQPT) + k * BLK + tid;
        const float* s = qbase + (size_t)q * 3;
        float qx = s[0], qy = s[1], qz = s[2];
        qx2[k] = (v2f){qx, qx}; qy2[k] = (v2f){qy, qy}; qz2[k] = (v2f){qz, qz};
        qn[k] = qx * qx + qy * qy + qz * qz;
    }
    __syncthreads();
    v2f acc0[FQPT], acc1[FQPT];
    #pragma unroll
    for (int k = 0; k < FQPT; ++k) {
        acc0[k] = (v2f){-FLT_MAX, -FLT_MAX};
        acc1[k] = (v2f){-FLT_MAX, -FLT_MAX};
    }
    #pragma unroll 2
    for (int m = 0; m < FCHUNK / 2; m += 2) {
        v4f u0 = pts[2*m + 0], v0 = pts[2*m + 1];
        v4f u1 = pts[2*m + 2], v1 = pts[2*m + 3];
        v2f X0 = __builtin_shufflevector(u0, u0, 0, 1);
        v2f Y0 = __builtin_shufflevector(u0, u0, 2, 3);
        v2f Z0 = __builtin_shufflevector(v0, v0, 0, 1);
        v2f W0 = __builtin_shufflevector(v0, v0, 2, 3);
        v2f X1 = __builtin_shufflevector(u1, u1, 0, 1);
        v2f Y1 = __builtin_shufflevector(u1, u1, 2, 3);
        v2f Z1 = __builtin_shufflevector(v1, v1, 0, 1);
        v2f W1 = __builtin_shufflevector(v1, v1, 2, 3);
        #pragma unroll
        for (int k = 0; k < FQPT; ++k) {
            v2f s0 = __builtin_elementwise_fma(qz2[k], Z0,
                      __builtin_elementwise_fma(qy2[k], Y0,
                       __builtin_elementwise_fma(qx2[k], X0, W0)));
            acc0[k] = __builtin_elementwise_max(acc0[k], s0);
            v2f s1 = __builtin_elementwise_fma(qz2[k], Z1,
                      __builtin_elementwise_fma(qy2[k], Y1,
                       __builtin_elementwise_fma(qx2[k], X1, W1)));
            acc1[k] = __builtin_elementwise_max(acc1[k], s1);
        }
    }
    unsigned qid = (unsigned)(dir * (BATCH * NPTS) + batch * NPTS + qt * (BLK * FQPT) + tid);
    #pragma unroll
    for (int k = 0; k < FQPT; ++k) {
        float mx = fmaxf(fmaxf(acc0[k].x, acc0[k].y), fmaxf(acc1[k].x, acc1[k].y));
        float d = fmaxf(qn[k] - 2.f * mx, 0.f);
        atomicMin(&mins[qid + k * BLK], __float_as_uint(d));
    }
}

__global__ __launch_bounds__(BLK) void sum_kernel(
    const unsigned* __restrict__ mins, float* __restrict__ out, int n, float scale)
{
    int i = blockIdx.x * BLK + threadIdx.x;
    int stride = gridDim.x * BLK;
    float v = 0.f;
    for (int idx = i; idx < n; idx += stride) v += __uint_as_float(mins[idx]);
    for (int off = 32; off > 0; off >>= 1) v += __shfl_down(v, off, 64);
    __shared__ float wsum[BLK / 64];
    int lane = threadIdx.x & 63, wid = threadIdx.x >> 6;
    if (lane == 0) wsum[wid] = v;
    __syncthreads();
    if (threadIdx.x == 0) {
        float t = 0.f;
        for (int w = 0; w < BLK / 64; ++w) t += wsum[w];
        atomicAdd(out, t * scale);
    }
}

extern "C" void kernel_launch(void* const* d_in, const int* in_sizes, int n_in,
                              void* d_out, int out_size, void* d_ws, size_t ws_size,
                              hipStream_t stream) {
    const float* p1 = (const float*)d_in[0];
    const float* p2 = (const float*)d_in[1];
    float* out = (float*)d_out;

    if (ws_size >= WS_NEED) {
        float* part1 = (float*)d_ws;                       // PCH x NROW (1 MB)
        float* part2 = part1 + (size_t)PCH * NROW;         // QTILES x NROW (4 MB)
        zero_out_kernel<<<1, 1, 0, stream>>>(out);
        cd_mfma_kernel<<<GRID, BLK, 0, stream>>>(p1, p2, part1, part2);
        min_sum_kernel<<<NROW / BLK, BLK, 0, stream>>>(part1, out, PCH,
                                                       1.f / (float)NROW);
        min_sum_kernel<<<NROW / BLK, BLK, 0, stream>>>(part2, out, QTILES,
                                                       1.f / (float)NROW);
    } else {
        unsigned* mins = (unsigned*)d_ws;
        init_kernel<<<TOTQ / BLK, BLK, 0, stream>>>(mins, out, TOTQ);
        cd_chunk_atomic_kernel<<<1024, BLK, 0, stream>>>(p1, p2, mins);
        sum_kernel<<<64, BLK, 0, stream>>>(mins, out, TOTQ, 1.f / (float)(BATCH * NPTS));
    }
}